// Round 2
// baseline (146.808 us; speedup 1.0000x reference)
//
#include <hip/hip_runtime.h>
#include <math.h>

#define BATCH 4
#define SEQ   4096
#define DIM   1024
#define VEC   4

// Per-d parameters: a = phazor = p/|p| * exp(-|p|), b = phazor_init.
__device__ __forceinline__ void load_params4(
    const float* __restrict__ phr, const float* __restrict__ phi,
    const float* __restrict__ pir, const float* __restrict__ pii,
    int d0, float* ar, float* ai, float* br, float* bi)
{
    float4 p_r = *reinterpret_cast<const float4*>(phr + d0);
    float4 p_i = *reinterpret_cast<const float4*>(phi + d0);
    float4 q_r = *reinterpret_cast<const float4*>(pir + d0);
    float4 q_i = *reinterpret_cast<const float4*>(pii + d0);
    float prv[VEC] = {p_r.x, p_r.y, p_r.z, p_r.w};
    float piv[VEC] = {p_i.x, p_i.y, p_i.z, p_i.w};
    float qrv[VEC] = {q_r.x, q_r.y, q_r.z, q_r.w};
    float qiv[VEC] = {q_i.x, q_i.y, q_i.z, q_i.w};
#pragma unroll
    for (int j = 0; j < VEC; ++j) {
        float mag = sqrtf(prv[j] * prv[j] + piv[j] * piv[j]);
        float s = expf(-mag) / mag;
        ar[j] = prv[j] * s;
        ai[j] = piv[j] * s;
        br[j] = qrv[j];
        bi[j] = qiv[j];
    }
}

// Pass 1: per-chunk local scan with zero initial state -> chunk carries.
template <int NC>
__global__ __launch_bounds__(256) void k_carry(
    const float* __restrict__ x,
    const float* __restrict__ phr, const float* __restrict__ phi,
    const float* __restrict__ pir, const float* __restrict__ pii,
    float2* __restrict__ carry)
{
    constexpr int S = SEQ / NC;
    const int d0 = (blockIdx.x * blockDim.x + threadIdx.x) * VEC;
    const int c = blockIdx.y, b = blockIdx.z;

    float ar[VEC], ai[VEC], br[VEC], bi[VEC];
    load_params4(phr, phi, pir, pii, d0, ar, ai, br, bi);

    const float* xp = x + ((size_t)b * SEQ + (size_t)c * S) * DIM + d0;
    float Cr[VEC] = {0.f, 0.f, 0.f, 0.f};
    float Ci[VEC] = {0.f, 0.f, 0.f, 0.f};
#pragma unroll 4
    for (int t = 0; t < S; ++t) {
        float4 xv = *reinterpret_cast<const float4*>(xp + (size_t)t * DIM);
        float xa[VEC] = {xv.x, xv.y, xv.z, xv.w};
#pragma unroll
        for (int j = 0; j < VEC; ++j) {
            float nr = fmaf(ar[j], Cr[j], fmaf(-ai[j], Ci[j], br[j] * xa[j]));
            float ni = fmaf(ar[j], Ci[j], fmaf( ai[j], Cr[j], bi[j] * xa[j]));
            Cr[j] = nr; Ci[j] = ni;
        }
    }
    float2* cp = carry + ((size_t)b * NC + c) * DIM + d0;
#pragma unroll
    for (int j = 0; j < VEC; ++j) cp[j] = make_float2(Cr[j], Ci[j]);
}

// Pass 2: per (b,d), serial scan over NC chunk carries with factor A = a^S,
// seeded with hidden[b,d] (= C[-1]).
template <int NC>
__global__ __launch_bounds__(256) void k_prefix(
    const float* __restrict__ phr, const float* __restrict__ phi,
    const float* __restrict__ hr,  const float* __restrict__ hi_,
    const float2* __restrict__ carry,
    float2* __restrict__ prefix)
{
    constexpr int S = SEQ / NC;
    const int idx = blockIdx.x * blockDim.x + threadIdx.x;  // b*DIM + d
    const int b = idx / DIM, d = idx % DIM;

    float pr = phr[d], pi = phi[d];
    float mag = sqrtf(pr * pr + pi * pi);
    float sc = expf(-mag) / mag;
    float ar = pr * sc, ai = pi * sc;

    // A = a^S via exponentiation by squaring.
    float Ar = 1.f, Ai = 0.f, sr = ar, si = ai;
    int e = S;
    while (e) {
        if (e & 1) {
            float nr = Ar * sr - Ai * si;
            Ai = Ar * si + Ai * sr;
            Ar = nr;
        }
        float nr = sr * sr - si * si;
        si = 2.f * sr * si;
        sr = nr;
        e >>= 1;
    }

    float2 cv[NC];
#pragma unroll
    for (int c = 0; c < NC; ++c)
        cv[c] = carry[((size_t)b * NC + c) * DIM + d];

    float Pr = hr[idx], Pi = hi_[idx];
#pragma unroll
    for (int c = 0; c < NC; ++c) {
        prefix[((size_t)b * NC + c) * DIM + d] = make_float2(Pr, Pi);
        float nr = fmaf(Ar, Pr, fmaf(-Ai, Pi, cv[c].x));
        float ni = fmaf(Ar, Pi, fmaf( Ai, Pr, cv[c].y));
        Pr = nr; Pi = ni;
    }
}

// Pass 3: rerun the chunk scan seeded with the chunk prefix.
// CPLX=true  -> write interleaved complex64 (2*B*L*D floats).
// CPLX=false -> write real part only (B*L*D floats).
template <int NC, bool CPLX>
__global__ __launch_bounds__(256) void k_out(
    const float* __restrict__ x,
    const float* __restrict__ phr, const float* __restrict__ phi,
    const float* __restrict__ pir, const float* __restrict__ pii,
    const float2* __restrict__ prefix,
    float* __restrict__ out)
{
    constexpr int S = SEQ / NC;
    const int d0 = (blockIdx.x * blockDim.x + threadIdx.x) * VEC;
    const int c = blockIdx.y, b = blockIdx.z;

    float ar[VEC], ai[VEC], br[VEC], bi[VEC];
    load_params4(phr, phi, pir, pii, d0, ar, ai, br, bi);

    float Cr[VEC], Ci[VEC];
    const float2* pp = prefix + ((size_t)b * NC + c) * DIM + d0;
#pragma unroll
    for (int j = 0; j < VEC; ++j) {
        float2 v = pp[j];
        Cr[j] = v.x; Ci[j] = v.y;
    }

    const float* xp = x + ((size_t)b * SEQ + (size_t)c * S) * DIM + d0;
    const size_t obase = ((size_t)b * SEQ + (size_t)c * S) * DIM + d0;
#pragma unroll 2
    for (int t = 0; t < S; ++t) {
        float4 xv = *reinterpret_cast<const float4*>(xp + (size_t)t * DIM);
        float xa[VEC] = {xv.x, xv.y, xv.z, xv.w};
#pragma unroll
        for (int j = 0; j < VEC; ++j) {
            float nr = fmaf(ar[j], Cr[j], fmaf(-ai[j], Ci[j], br[j] * xa[j]));
            float ni = fmaf(ar[j], Ci[j], fmaf( ai[j], Cr[j], bi[j] * xa[j]));
            Cr[j] = nr; Ci[j] = ni;
        }
        if (CPLX) {
            float4* dst = reinterpret_cast<float4*>(out + 2 * (obase + (size_t)t * DIM));
            dst[0] = make_float4(Cr[0], Ci[0], Cr[1], Ci[1]);
            dst[1] = make_float4(Cr[2], Ci[2], Cr[3], Ci[3]);
        } else {
            *reinterpret_cast<float4*>(out + obase + (size_t)t * DIM) =
                make_float4(Cr[0], Cr[1], Cr[2], Cr[3]);
        }
    }
}

// Scratch-free fallback: one thread per (b,d), serial scan over all of SEQ.
// Slow but provably in-bounds; only used if ws_size is too small.
template <bool CPLX>
__global__ void k_serial(
    const float* __restrict__ x,
    const float* __restrict__ phr, const float* __restrict__ phi,
    const float* __restrict__ pir, const float* __restrict__ pii,
    const float* __restrict__ hr,  const float* __restrict__ hi_,
    float* __restrict__ out)
{
    const int idx = blockIdx.x * blockDim.x + threadIdx.x;  // b*DIM + d
    if (idx >= BATCH * DIM) return;
    const int b = idx / DIM, d = idx % DIM;

    float pr = phr[d], pi = phi[d];
    float mag = sqrtf(pr * pr + pi * pi);
    float sc = expf(-mag) / mag;
    float ar = pr * sc, ai = pi * sc;
    float br = pir[d], bi = pii[d];

    float Cr = hr[idx], Ci = hi_[idx];
    const float* xp = x + (size_t)b * SEQ * DIM + d;
    for (int t = 0; t < SEQ; ++t) {
        float xv = xp[(size_t)t * DIM];
        float nr = fmaf(ar, Cr, fmaf(-ai, Ci, br * xv));
        float ni = fmaf(ar, Ci, fmaf( ai, Cr, bi * xv));
        Cr = nr; Ci = ni;
        size_t o = ((size_t)b * SEQ + t) * DIM + d;
        if (CPLX) {
            reinterpret_cast<float2*>(out)[o] = make_float2(Cr, Ci);
        } else {
            out[o] = Cr;
        }
    }
}

template <int NC, bool CPLX>
static void run_all(const float* x, const float* hr, const float* hi_,
                    const float* phr, const float* phi,
                    const float* pir, const float* pii,
                    float* out, void* d_ws, hipStream_t stream)
{
    float2* carry = (float2*)d_ws;
    float2* prefix = carry + (size_t)BATCH * NC * DIM;

    dim3 blk(256);
    dim3 g1(DIM / (256 * VEC), NC, BATCH);
    k_carry<NC><<<g1, blk, 0, stream>>>(x, phr, phi, pir, pii, carry);
    k_prefix<NC><<<dim3(BATCH * DIM / 256), blk, 0, stream>>>(
        phr, phi, hr, hi_, carry, prefix);
    k_out<NC, CPLX><<<g1, blk, 0, stream>>>(x, phr, phi, pir, pii, prefix, out);
}

template <bool CPLX>
static void dispatch(const float* x, const float* hr, const float* hi_,
                     const float* phr, const float* phi,
                     const float* pir, const float* pii,
                     float* out, void* d_ws, size_t ws_size, hipStream_t stream)
{
    // ws need for NC chunks: carries + prefixes = 2 * B * NC * DIM * 8 bytes
    auto need = [](int nc) { return (size_t)2 * BATCH * nc * DIM * sizeof(float2); };

    if (ws_size >= need(64))
        run_all<64, CPLX>(x, hr, hi_, phr, phi, pir, pii, out, d_ws, stream);
    else if (ws_size >= need(32))
        run_all<32, CPLX>(x, hr, hi_, phr, phi, pir, pii, out, d_ws, stream);
    else if (ws_size >= need(16))
        run_all<16, CPLX>(x, hr, hi_, phr, phi, pir, pii, out, d_ws, stream);
    else
        k_serial<CPLX><<<dim3((BATCH * DIM + 255) / 256), dim3(256), 0, stream>>>(
            x, phr, phi, pir, pii, hr, hi_, out);
}

extern "C" void kernel_launch(void* const* d_in, const int* in_sizes, int n_in,
                              void* d_out, int out_size, void* d_ws, size_t ws_size,
                              hipStream_t stream) {
    const float* x   = (const float*)d_in[0];
    const float* hr  = (const float*)d_in[1];
    const float* hi_ = (const float*)d_in[2];
    const float* phr = (const float*)d_in[3];
    const float* phi = (const float*)d_in[4];
    const float* pir = (const float*)d_in[5];
    const float* pii = (const float*)d_in[6];
    float* out = (float*)d_out;

    const size_t total = (size_t)BATCH * SEQ * DIM;
    // out_size >= 2*total  -> buffer holds interleaved complex64 (re,im pairs)
    // otherwise            -> buffer holds exactly total floats: write real part
    if ((size_t)out_size >= 2 * total)
        dispatch<true >(x, hr, hi_, phr, phi, pir, pii, out, d_ws, ws_size, stream);
    else
        dispatch<false>(x, hr, hi_, phr, phi, pir, pii, out, d_ws, ws_size, stream);
}